// Round 5
// baseline (50.518 us; speedup 1.0000x reference)
//
#include <hip/hip_runtime.h>
#include <math.h>

#define W_POS 0.1f
#define W_SCALE 0.1f
#define W_ROT 0.1f
#define W_COLOR 0.1f

#define RPT 4            // rows per lane
#define CHUNK 128        // candidates per chunk (2 KB LDS)
#define NSPLIT 64        // 8192 / CHUNK

__device__ __forceinline__ unsigned umed3(unsigned a, unsigned b, unsigned c) {
    unsigned d;
    asm("v_med3_u32 %0, %1, %2, %3" : "=v"(d) : "v"(a), "v"(b), "v"(c));
    return d;
}
__device__ __forceinline__ unsigned umin_(unsigned a, unsigned b) {
    unsigned d;
    asm("v_min_u32 %0, %1, %2" : "=v"(d) : "v"(a), "v"(b));
    return d;
}

// Insert into ascending sorted 7-list E[0..6] (drops current max).
// E[k] = min(E[k], max(E[k-1], key)) == med3(key, E[k-1], E[k]) since sorted.
// Top-down order: every update reads OLD neighbor -> 7 independent ops.
#define INSERT7A(E, keyv) do { unsigned _k = (keyv);   \
    E[6] = umed3(_k, E[5], E[6]);                      \
    E[5] = umed3(_k, E[4], E[5]);                      \
    E[4] = umed3(_k, E[3], E[4]);                      \
    E[3] = umed3(_k, E[2], E[3]);                      \
    E[2] = umed3(_k, E[1], E[2]);                      \
    E[1] = umed3(_k, E[0], E[1]);                      \
    E[0] = umin_(E[0], _k);  } while (0)

// Kernel 1: each lane owns RPT=4 rows; block covers 1024 rows x one
// 128-candidate chunk staged in LDS (uniform-address broadcast reads).
// Writes one sorted 7-list per (chunk,row).
__global__ __launch_bounds__(256) void pass_kernel(
    const float* __restrict__ pos,
    unsigned* __restrict__ lists, int n)
{
    const int tid = threadIdx.x;
    const int rowbase = blockIdx.x * 1024 + (tid >> 6) * 256 + (tid & 63);
    const int s = blockIdx.y;

    __shared__ float4 cand[CHUNK];
    if (tid < CHUNK) {
        int j = s * CHUNK + tid;
        float x = pos[3 * j], y = pos[3 * j + 1], z = pos[3 * j + 2];
        cand[tid] = make_float4(x, y, z, x * x + y * y + z * z);
    }

    float qx2[RPT], qy2[RPT], qz2[RPT], sqi[RPT];
#pragma unroll
    for (int k = 0; k < RPT; ++k) {
        int r = rowbase + 64 * k;
        float x = pos[3 * r], y = pos[3 * r + 1], z = pos[3 * r + 2];
        qx2[k] = -2.0f * x; qy2[k] = -2.0f * y; qz2[k] = -2.0f * z;
        sqi[k] = x * x + y * y + z * z;
    }

    unsigned e[RPT][7];
#pragma unroll
    for (int k = 0; k < RPT; ++k)
#pragma unroll
        for (int t = 0; t < 7; ++t) e[k][t] = 0xFFFFFFFFu;

    __syncthreads();

    const unsigned jbase = (unsigned)(s * CHUNK);
#pragma unroll 8
    for (int t = 0; t < CHUNK; ++t) {
        float4 p = cand[t];       // uniform address: HW broadcast, 1 read/4 rows
        unsigned jkey = jbase + (unsigned)t;
#pragma unroll
        for (int k = 0; k < RPT; ++k) {
            float c0 = fmaf(qz2[k], p.z, sqi[k]);
            float c1 = fmaf(qy2[k], p.y, c0);
            float c2 = fmaf(qx2[k], p.x, c1);
            float d2 = c2 + p.w;   // no clamp: negative (self rounding) keys
                                   // get the sign bit -> huge -> auto-excluded
            unsigned key = (__float_as_uint(d2) & 0xFFFFE000u) | jkey;
            INSERT7A(e[k], key);
        }
    }

#pragma unroll
    for (int k = 0; k < RPT; ++k) {
        int r = rowbase + 64 * k;
        unsigned* dst = lists + (((size_t)s * n + r) << 3);
        *(uint4*)dst = make_uint4(e[k][0], e[k][1], e[k][2], e[k][3]);
        *(uint4*)(dst + 4) = make_uint4(e[k][4], e[k][5], e[k][6], 0xFFFFFFFFu);
    }
}

// Kernel 2: one thread per row: merge the 64 sorted 7-lists, all per-row loss
// terms (incl. elementwise), block-reduce (double) -> bpart[32].
__global__ __launch_bounds__(256) void merge_kernel(
    const float* __restrict__ pos,
    const float* __restrict__ scales,
    const float* __restrict__ rots,
    const float* __restrict__ colors,
    const unsigned* __restrict__ lists,
    double* __restrict__ bpart, int n)
{
    const int r = blockIdx.x * 256 + threadIdx.x;

    unsigned e[7];
#pragma unroll
    for (int t = 0; t < 7; ++t) e[t] = 0xFFFFFFFFu;

#pragma unroll 4
    for (int s2 = 0; s2 < NSPLIT; ++s2) {
        const uint4* p4 = (const uint4*)(lists + (((size_t)s2 * n + r) << 3));
        uint4 a = p4[0], b = p4[1];
        INSERT7A(e, a.x); INSERT7A(e, a.y); INSERT7A(e, a.z); INSERT7A(e, a.w);
        INSERT7A(e, b.x); INSERT7A(e, b.y); INSERT7A(e, b.z);
    }

    // self-exclusion (self may sit anywhere, or be absent if d2 rounded negative)
    const unsigned M = 0x1FFFu;
    int spos = ((e[0] & M) == (unsigned)r) ? 0 :
               ((e[1] & M) == (unsigned)r) ? 1 :
               ((e[2] & M) == (unsigned)r) ? 2 :
               ((e[3] & M) == (unsigned)r) ? 3 :
               ((e[4] & M) == (unsigned)r) ? 4 :
               ((e[5] & M) == (unsigned)r) ? 5 :
               ((e[6] & M) == (unsigned)r) ? 6 : 7;
    unsigned u0 = (spos == 0) ? e[1] : e[0];
    unsigned u1 = (spos <= 1) ? e[2] : e[1];
    unsigned u2 = (spos <= 2) ? e[3] : e[2];
    unsigned u3 = (spos <= 3) ? e[4] : e[3];
    unsigned u4 = (spos <= 4) ? e[5] : e[4];

    // exact recompute of 2nd-NN distance (selection keys were truncated)
    float qx = pos[3 * r], qy = pos[3 * r + 1], qz = pos[3 * r + 2];
    float sq = qx * qx + qy * qy + qz * qz;
    const int i2 = (int)(u1 & M);
    float px = pos[3 * i2], py = pos[3 * i2 + 1], pz = pos[3 * i2 + 2];
    float sp = px * px + py * py + pz * pz;
    float dot2 = fmaf(qx, px, fmaf(qy, py, qz * pz));
    float d2e = fmaxf(sq + sp - 2.0f * dot2, 0.0f);
    float min_d = sqrtf(d2e);

    // color smoothness over the 5 nearest off-diag neighbors
    float c0 = colors[3 * r], c1 = colors[3 * r + 1], c2 = colors[3 * r + 2];
    float cs = 0.0f;
    unsigned nb[5] = { u0, u1, u2, u3, u4 };
#pragma unroll
    for (int k = 0; k < 5; ++k) {
        int nidx = (int)(nb[k] & M);
        cs += fabsf(c0 - colors[3 * nidx]);
        cs += fabsf(c1 - colors[3 * nidx + 1]);
        cs += fabsf(c2 - colors[3 * nidx + 2]);
    }

    // elementwise losses (scale / rotation / color-center)
    const float invn = 1.0f / (float)n;
    float s0 = scales[3 * r], s1 = scales[3 * r + 1], s2 = scales[3 * r + 2];
    float m = (s0 + s1 + s2) * (1.0f / 3.0f);
    float var = ((s0 - m) * (s0 - m) + (s1 - m) * (s1 - m) + (s2 - m) * (s2 - m)) * 0.5f;
    float al = fabsf(s0 - 1.0f) + fabsf(s1 - 1.0f) + fabsf(s2 - 1.0f);
    float r0 = rots[4 * r], r1 = rots[4 * r + 1], r2 = rots[4 * r + 2], r3 = rots[4 * r + 3];
    float nm = sqrtf(r0 * r0 + r1 * r1 + r2 * r2 + r3 * r3);

    float contrib =
        cs * (W_COLOR * invn / 15.0f) +
        expf(-min_d) * (W_POS * invn) +
        W_SCALE * (al * (invn / 3.0f) + var * invn) +
        W_ROT * (nm - 1.0f) * (nm - 1.0f) * invn +
        W_COLOR * ((c0 - .5f) * (c0 - .5f) + (c1 - .5f) * (c1 - .5f) + (c2 - .5f) * (c2 - .5f)) * (invn / 3.0f);

    __shared__ double sm[256];
    sm[threadIdx.x] = (double)contrib;
    __syncthreads();
    for (int step = 128; step; step >>= 1) {
        if ((int)threadIdx.x < step) sm[threadIdx.x] += sm[threadIdx.x + step];
        __syncthreads();
    }
    if (threadIdx.x == 0) bpart[blockIdx.x] = sm[0];
}

// Kernel 3: deterministic final sum of the 32 block partials.
__global__ void final_kernel(const double* __restrict__ bpart, float* __restrict__ out)
{
    const int lane = threadIdx.x & 63;
    double acc = (lane < 32) ? bpart[lane] : 0.0;
#pragma unroll
    for (int off = 32; off; off >>= 1)
        acc += __shfl_xor(acc, off, 64);
    if (lane == 0) out[0] = (float)acc;
}

extern "C" void kernel_launch(void* const* d_in, const int* in_sizes, int n_in,
                              void* d_out, int out_size, void* d_ws, size_t ws_size,
                              hipStream_t stream) {
    const float* pos = (const float*)d_in[0];
    const float* scales = (const float*)d_in[1];
    const float* rots = (const float*)d_in[2];
    const float* colors = (const float*)d_in[3];
    int n = in_sizes[0] / 3;  // 8192

    char* ws = (char*)d_ws;
    unsigned* lists = (unsigned*)ws;              ws += (size_t)NSPLIT * n * 32;
    double* bpart = (double*)ws;

    pass_kernel<<<dim3(n / 1024, NSPLIT), 256, 0, stream>>>(pos, lists, n);
    merge_kernel<<<n / 256, 256, 0, stream>>>(pos, scales, rots, colors, lists, bpart, n);
    final_kernel<<<1, 64, 0, stream>>>(bpart, (float*)d_out);
}

// Round 6
// 41.943 us; speedup vs baseline: 1.2044x; 1.2044x over previous
//
#include <hip/hip_runtime.h>
#include <math.h>

#define W_POS 0.1f
#define W_SCALE 0.1f
#define W_ROT 0.1f
#define W_COLOR 0.1f

#define RPT 2            // rows per lane
#define CHUNK 256        // candidates per chunk (4 KB LDS)
#define NSPLIT 32        // 8192 / CHUNK

__device__ __forceinline__ unsigned umed3(unsigned a, unsigned b, unsigned c) {
    unsigned d;
    asm("v_med3_u32 %0, %1, %2, %3" : "=v"(d) : "v"(a), "v"(b), "v"(c));
    return d;
}
__device__ __forceinline__ unsigned umin_(unsigned a, unsigned b) {
    unsigned d;
    asm("v_min_u32 %0, %1, %2" : "=v"(d) : "v"(a), "v"(b));
    return d;
}

// Insert into ascending sorted 7-list E[0..6] (drops current max).
// E[k] = min(E[k], max(E[k-1], key)) == med3(key, E[k-1], E[k]) since sorted.
// Top-down order: every update reads OLD neighbor -> 7 independent ops.
#define INSERT7A(E, keyv) do { unsigned _k = (keyv);   \
    E[6] = umed3(_k, E[5], E[6]);                      \
    E[5] = umed3(_k, E[4], E[5]);                      \
    E[4] = umed3(_k, E[3], E[4]);                      \
    E[3] = umed3(_k, E[2], E[3]);                      \
    E[2] = umed3(_k, E[1], E[2]);                      \
    E[1] = umed3(_k, E[0], E[1]);                      \
    E[0] = umin_(E[0], _k);  } while (0)

// Kernel 1: each thread owns RPT=2 rows; block covers 512 rows x one
// 256-candidate chunk staged in LDS (uniform-address broadcast reads).
// Writes one sorted 7-list per (chunk,row). Also zeroes the merge counter.
__global__ __launch_bounds__(256) void pass_kernel(
    const float* __restrict__ pos,
    unsigned* __restrict__ lists,
    unsigned* __restrict__ ctr, int n)
{
    const int tid = threadIdx.x;
    const int s = blockIdx.y;
    const int r0 = blockIdx.x * 512 + tid;     // row 0; row 1 = r0 + 256

    if (blockIdx.x == 0 && blockIdx.y == 0 && tid == 0) ctr[0] = 0;

    __shared__ float4 cand[CHUNK];
    {
        int j = s * CHUNK + tid;
        float x = pos[3 * j], y = pos[3 * j + 1], z = pos[3 * j + 2];
        cand[tid] = make_float4(x, y, z, x * x + y * y + z * z);
    }

    float qx2[RPT], qy2[RPT], qz2[RPT], sqi[RPT];
#pragma unroll
    for (int k = 0; k < RPT; ++k) {
        int r = r0 + 256 * k;
        float x = pos[3 * r], y = pos[3 * r + 1], z = pos[3 * r + 2];
        qx2[k] = -2.0f * x; qy2[k] = -2.0f * y; qz2[k] = -2.0f * z;
        sqi[k] = x * x + y * y + z * z;
    }

    unsigned e[RPT][7];
#pragma unroll
    for (int k = 0; k < RPT; ++k)
#pragma unroll
        for (int t = 0; t < 7; ++t) e[k][t] = 0xFFFFFFFFu;

    __syncthreads();

    const unsigned jbase = (unsigned)(s * CHUNK);
#pragma unroll 8
    for (int t = 0; t < CHUNK; ++t) {
        float4 p = cand[t];     // uniform address: HW broadcast, 1 read / 2 rows
        unsigned jkey = jbase + (unsigned)t;
#pragma unroll
        for (int k = 0; k < RPT; ++k) {
            float c0 = fmaf(qz2[k], p.z, sqi[k]);
            float c1 = fmaf(qy2[k], p.y, c0);
            float c2 = fmaf(qx2[k], p.x, c1);
            float d2 = c2 + p.w;  // no clamp: if self rounds negative the sign
                                  // bit makes the key huge -> auto-excluded
            unsigned key = (__float_as_uint(d2) & 0xFFFFE000u) | jkey;  // v_and_or_b32
            INSERT7A(e[k], key);
        }
    }

#pragma unroll
    for (int k = 0; k < RPT; ++k) {
        int r = r0 + 256 * k;
        unsigned* dst = lists + (((size_t)s * n + r) << 3);
        *(uint4*)dst = make_uint4(e[k][0], e[k][1], e[k][2], e[k][3]);
        *(uint4*)(dst + 4) = make_uint4(e[k][4], e[k][5], e[k][6], 0xFFFFFFFFu);
    }
}

// Kernel 2: one thread per row: merge the 32 sorted 7-lists, all per-row loss
// terms, block-reduce (double). Last finished block sums the 64 partials.
__global__ __launch_bounds__(128) void merge_kernel(
    const float* __restrict__ pos,
    const float* __restrict__ scales,
    const float* __restrict__ rots,
    const float* __restrict__ colors,
    const unsigned* __restrict__ lists,
    double* __restrict__ bpart,
    unsigned* __restrict__ ctr,
    float* __restrict__ out, int n)
{
    const int r = blockIdx.x * 128 + threadIdx.x;

    unsigned e[7];
#pragma unroll
    for (int t = 0; t < 7; ++t) e[t] = 0xFFFFFFFFu;

#pragma unroll 4
    for (int s2 = 0; s2 < NSPLIT; ++s2) {
        const uint4* p4 = (const uint4*)(lists + (((size_t)s2 * n + r) << 3));
        uint4 a = p4[0], b = p4[1];
        INSERT7A(e, a.x); INSERT7A(e, a.y); INSERT7A(e, a.z); INSERT7A(e, a.w);
        INSERT7A(e, b.x); INSERT7A(e, b.y); INSERT7A(e, b.z);
    }

    // self-exclusion (self may sit anywhere, or be absent if d2 rounded negative)
    const unsigned M = 0x1FFFu;
    int spos = ((e[0] & M) == (unsigned)r) ? 0 :
               ((e[1] & M) == (unsigned)r) ? 1 :
               ((e[2] & M) == (unsigned)r) ? 2 :
               ((e[3] & M) == (unsigned)r) ? 3 :
               ((e[4] & M) == (unsigned)r) ? 4 :
               ((e[5] & M) == (unsigned)r) ? 5 :
               ((e[6] & M) == (unsigned)r) ? 6 : 7;
    unsigned u0 = (spos == 0) ? e[1] : e[0];
    unsigned u1 = (spos <= 1) ? e[2] : e[1];
    unsigned u2 = (spos <= 2) ? e[3] : e[2];
    unsigned u3 = (spos <= 3) ? e[4] : e[3];
    unsigned u4 = (spos <= 4) ? e[5] : e[4];

    // exact recompute of 2nd-NN distance (selection keys were truncated)
    float qx = pos[3 * r], qy = pos[3 * r + 1], qz = pos[3 * r + 2];
    float sq = qx * qx + qy * qy + qz * qz;
    const int i2 = (int)(u1 & M);
    float px = pos[3 * i2], py = pos[3 * i2 + 1], pz = pos[3 * i2 + 2];
    float sp = px * px + py * py + pz * pz;
    float dot2 = fmaf(qx, px, fmaf(qy, py, qz * pz));
    float d2e = fmaxf(sq + sp - 2.0f * dot2, 0.0f);
    float min_d = sqrtf(d2e);

    // color smoothness over the 5 nearest off-diag neighbors
    float c0 = colors[3 * r], c1 = colors[3 * r + 1], c2 = colors[3 * r + 2];
    float cs = 0.0f;
    unsigned nb[5] = { u0, u1, u2, u3, u4 };
#pragma unroll
    for (int k = 0; k < 5; ++k) {
        int nidx = (int)(nb[k] & M);
        cs += fabsf(c0 - colors[3 * nidx]);
        cs += fabsf(c1 - colors[3 * nidx + 1]);
        cs += fabsf(c2 - colors[3 * nidx + 2]);
    }

    // elementwise losses (scale / rotation / color-center)
    const float invn = 1.0f / (float)n;
    float s0 = scales[3 * r], s1 = scales[3 * r + 1], s2 = scales[3 * r + 2];
    float m = (s0 + s1 + s2) * (1.0f / 3.0f);
    float var = ((s0 - m) * (s0 - m) + (s1 - m) * (s1 - m) + (s2 - m) * (s2 - m)) * 0.5f;
    float al = fabsf(s0 - 1.0f) + fabsf(s1 - 1.0f) + fabsf(s2 - 1.0f);
    float r0 = rots[4 * r], r1 = rots[4 * r + 1], r2 = rots[4 * r + 2], r3 = rots[4 * r + 3];
    float nm = sqrtf(r0 * r0 + r1 * r1 + r2 * r2 + r3 * r3);

    float contrib =
        cs * (W_COLOR * invn / 15.0f) +
        expf(-min_d) * (W_POS * invn) +
        W_SCALE * (al * (invn / 3.0f) + var * invn) +
        W_ROT * (nm - 1.0f) * (nm - 1.0f) * invn +
        W_COLOR * ((c0 - .5f) * (c0 - .5f) + (c1 - .5f) * (c1 - .5f) + (c2 - .5f) * (c2 - .5f)) * (invn / 3.0f);

    __shared__ double sm[128];
    sm[threadIdx.x] = (double)contrib;
    __syncthreads();
    for (int step = 64; step; step >>= 1) {
        if ((int)threadIdx.x < step) sm[threadIdx.x] += sm[threadIdx.x + step];
        __syncthreads();
    }
    __shared__ int lastflag;
    if (threadIdx.x == 0) {
        bpart[blockIdx.x] = sm[0];
        __threadfence();                         // release: publish partial
        unsigned old = atomicAdd(ctr, 1u);       // device-scope by default
        lastflag = (old == 63) ? 1 : 0;
    }
    __syncthreads();
    if (!lastflag || threadIdx.x >= 64) return;

    // last block: deterministic fixed-tree sum of the 64 partials
    __threadfence();                             // acquire
    double acc = bpart[threadIdx.x];
#pragma unroll
    for (int off = 32; off; off >>= 1)
        acc += __shfl_xor(acc, off, 64);
    if (threadIdx.x == 0) out[0] = (float)acc;
}

extern "C" void kernel_launch(void* const* d_in, const int* in_sizes, int n_in,
                              void* d_out, int out_size, void* d_ws, size_t ws_size,
                              hipStream_t stream) {
    const float* pos = (const float*)d_in[0];
    const float* scales = (const float*)d_in[1];
    const float* rots = (const float*)d_in[2];
    const float* colors = (const float*)d_in[3];
    int n = in_sizes[0] / 3;  // 8192

    char* ws = (char*)d_ws;
    unsigned* lists = (unsigned*)ws;              ws += (size_t)NSPLIT * n * 32;
    double* bpart = (double*)ws;                  ws += 64 * sizeof(double);
    unsigned* ctr = (unsigned*)ws;

    pass_kernel<<<dim3(n / 512, NSPLIT), 256, 0, stream>>>(pos, lists, ctr, n);
    merge_kernel<<<n / 128, 128, 0, stream>>>(pos, scales, rots, colors, lists, bpart, ctr,
                                              (float*)d_out, n);
}

// Round 7
// 38.211 us; speedup vs baseline: 1.3221x; 1.0977x over previous
//
#include <hip/hip_runtime.h>
#include <math.h>

#define W_POS 0.1f
#define W_SCALE 0.1f
#define W_ROT 0.1f
#define W_COLOR 0.1f

__device__ __forceinline__ unsigned umed3(unsigned a, unsigned b, unsigned c) {
    unsigned d;
    asm("v_med3_u32 %0, %1, %2, %3" : "=v"(d) : "v"(a), "v"(b), "v"(c));
    return d;
}
__device__ __forceinline__ unsigned umin_(unsigned a, unsigned b) {
    unsigned d;
    asm("v_min_u32 %0, %1, %2" : "=v"(d) : "v"(a), "v"(b));
    return d;
}

// Insert into ascending sorted 7-list E[0..6] (drops current max).
// E[k] = min(E[k], max(E[k-1], key)) == med3(key, E[k-1], E[k]) since sorted.
// Top-down order: every update reads OLD neighbor -> 7 independent ops.
#define INSERT7A(E, keyv) do { unsigned _k = (keyv);   \
    E[6] = umed3(_k, E[5], E[6]);                      \
    E[5] = umed3(_k, E[4], E[5]);                      \
    E[4] = umed3(_k, E[3], E[4]);                      \
    E[3] = umed3(_k, E[2], E[3]);                      \
    E[2] = umed3(_k, E[1], E[2]);                      \
    E[1] = umed3(_k, E[0], E[1]);                      \
    E[0] = umin_(E[0], _k);  } while (0)

// 7-round cross-lane merge of 64 sorted lists: OUT[t] = t-th smallest overall.
// Keys unique (index in low bits) -> exactly one owner lane pops per round.
#define WAVE_MERGE7(E, OUT) do {                                     \
    _Pragma("unroll")                                                \
    for (int _t = 0; _t < 7; ++_t) {                                 \
        unsigned _v = E[0];                                          \
        _Pragma("unroll")                                            \
        for (int _o = 32; _o; _o >>= 1)                              \
            _v = umin_(_v, (unsigned)__shfl_xor((int)_v, _o, 64));   \
        OUT[_t] = _v;                                                \
        bool _own = (E[0] == _v);                                    \
        _Pragma("unroll")                                            \
        for (int _m = 0; _m < 6; ++_m) E[_m] = _own ? E[_m+1] : E[_m]; \
        E[6] = _own ? 0xFFFFFFFFu : E[6];                            \
    } } while (0)

// One wave owns rows {2*wid, 2*wid+1} and scans ALL candidates (lane-split).
// No intermediate lists, no merge kernel. All waves issue identical candidate
// addresses -> the shared stream stays L1/L2-resident.
__global__ __launch_bounds__(256, 4) void main_kernel(
    const float* __restrict__ pos,
    const float* __restrict__ scales,
    const float* __restrict__ rots,
    const float* __restrict__ colors,
    double* __restrict__ partials, int n)
{
    const int lane = threadIdx.x & 63;
    const int wid = blockIdx.x * 4 + (threadIdx.x >> 6);
    const int rA = wid * 2, rB = rA + 1;

    const float ax = pos[3*rA], ay = pos[3*rA+1], az = pos[3*rA+2];
    const float bx = pos[3*rB], by = pos[3*rB+1], bz = pos[3*rB+2];

    unsigned ea[7], eb[7];
#pragma unroll
    for (int t = 0; t < 7; ++t) { ea[t] = 0xFFFFFFFFu; eb[t] = 0xFFFFFFFFu; }

    // hot loop: candidate j = t*64 + lane (identical across all waves)
#pragma unroll 8
    for (int t = 0; t < 128; ++t) {
        const int j = t * 64 + lane;
        float px = pos[3*j], py = pos[3*j+1], pz = pos[3*j+2];
        // subtract form: exact 0 for self, always >= 0, no prep buffer needed.
        float dxa = ax - px, dya = ay - py, dza = az - pz;
        float d2a = fmaf(dza, dza, fmaf(dya, dya, dxa * dxa));
        // truncate low 13 mantissa bits, pack index: orders like top_k
        // (distance asc, then smaller index)
        unsigned ka = (__float_as_uint(d2a) & 0xFFFFE000u) | (unsigned)j;
        INSERT7A(ea, ka);
        float dxb = bx - px, dyb = by - py, dzb = bz - pz;
        float d2b = fmaf(dzb, dzb, fmaf(dyb, dyb, dxb * dxb));
        unsigned kb = (__float_as_uint(d2b) & 0xFFFFE000u) | (unsigned)j;
        INSERT7A(eb, kb);
    }

    unsigned oa[7], ob[7];
    WAVE_MERGE7(ea, oa);   // row A: 7 smallest, uniform across lanes
    WAVE_MERGE7(eb, ob);   // row B

    // ---- epilogue: half-wave per row, sub-lane l per term ----
    const int half = lane >> 5;      // 0 -> row A, 1 -> row B
    const int l = lane & 31;
    const int r = rA + half;
    const unsigned M = 0x1FFFu;
    const unsigned rr = (unsigned)r;

    unsigned o0 = half ? ob[0] : oa[0];
    unsigned o1 = half ? ob[1] : oa[1];
    unsigned o2 = half ? ob[2] : oa[2];
    unsigned o3 = half ? ob[3] : oa[3];
    unsigned o4 = half ? ob[4] : oa[4];
    unsigned o5 = half ? ob[5] : oa[5];
    unsigned o6 = half ? ob[6] : oa[6];

    // self-exclusion (self is o0 in practice — exact d2=0 — but stay general)
    int spos = ((o0 & M) == rr) ? 0 :
               ((o1 & M) == rr) ? 1 :
               ((o2 & M) == rr) ? 2 :
               ((o3 & M) == rr) ? 3 :
               ((o4 & M) == rr) ? 4 :
               ((o5 & M) == rr) ? 5 :
               ((o6 & M) == rr) ? 6 : 7;
    unsigned u0 = (spos == 0) ? o1 : o0;
    unsigned u1 = (spos <= 1) ? o2 : o1;
    unsigned u2 = (spos <= 2) ? o3 : o2;
    unsigned u3 = (spos <= 3) ? o4 : o3;
    unsigned u4 = (spos <= 4) ? o5 : o4;

    const float invn = 1.0f / (float)n;
    float contrib = 0.0f;
    if (l < 15) {
        // 5 nearest off-diag neighbors x 3 channels
        int t = l / 3, ch = l - 3 * t;
        unsigned uk = u0;
        if (t == 1) uk = u1;
        if (t == 2) uk = u2;
        if (t == 3) uk = u3;
        if (t == 4) uk = u4;
        int nidx = (int)(uk & M);
        contrib = fabsf(colors[3*r+ch] - colors[3*nidx+ch]) * (W_COLOR * invn / 15.0f);
    } else if (l == 15) {
        // exact recompute of 2nd-NN distance with the REFERENCE formula
        int i2 = (int)(u1 & M);
        float qx = pos[3*r], qy = pos[3*r+1], qz = pos[3*r+2];
        float px = pos[3*i2], py = pos[3*i2+1], pz = pos[3*i2+2];
        float sq = qx*qx + qy*qy + qz*qz;
        float sp = px*px + py*py + pz*pz;
        float dot = fmaf(qx, px, fmaf(qy, py, qz * pz));
        float d2e = fmaxf(sq + sp - 2.0f * dot, 0.0f);
        contrib = expf(-sqrtf(d2e)) * (W_POS * invn);
    } else if (l == 16) {
        float s0 = scales[3*r], s1 = scales[3*r+1], s2 = scales[3*r+2];
        float m = (s0 + s1 + s2) * (1.0f / 3.0f);
        float var = ((s0-m)*(s0-m) + (s1-m)*(s1-m) + (s2-m)*(s2-m)) * 0.5f;
        float al = fabsf(s0 - 1.0f) + fabsf(s1 - 1.0f) + fabsf(s2 - 1.0f);
        contrib = W_SCALE * (al * (invn / 3.0f) + var * invn);
    } else if (l == 17) {
        float r0 = rots[4*r], r1 = rots[4*r+1], r2 = rots[4*r+2], r3 = rots[4*r+3];
        float nm = sqrtf(r0*r0 + r1*r1 + r2*r2 + r3*r3);
        contrib = W_ROT * (nm - 1.0f) * (nm - 1.0f) * invn;
    } else if (l == 18) {
        float c0 = colors[3*r], c1 = colors[3*r+1], c2 = colors[3*r+2];
        contrib = W_COLOR * ((c0-.5f)*(c0-.5f) + (c1-.5f)*(c1-.5f) + (c2-.5f)*(c2-.5f)) * (invn / 3.0f);
    }

    // wave sum (fixed butterfly, f64) -> one partial per wave
    double cd = (double)contrib;
#pragma unroll
    for (int off = 32; off; off >>= 1)
        cd += __shfl_xor(cd, off, 64);
    if (lane == 0) partials[wid] = cd;
}

// Deterministic final sum of n/2 wave partials (fixed order + tree).
__global__ __launch_bounds__(256) void final_kernel(
    const double* __restrict__ partials, float* __restrict__ out, int nw)
{
    __shared__ double sm[256];
    double s = 0.0;
    for (int k = threadIdx.x; k < nw; k += 256) s += partials[k];
    sm[threadIdx.x] = s;
    __syncthreads();
    for (int step = 128; step; step >>= 1) {
        if ((int)threadIdx.x < step) sm[threadIdx.x] += sm[threadIdx.x + step];
        __syncthreads();
    }
    if (threadIdx.x == 0) out[0] = (float)sm[0];
}

extern "C" void kernel_launch(void* const* d_in, const int* in_sizes, int n_in,
                              void* d_out, int out_size, void* d_ws, size_t ws_size,
                              hipStream_t stream) {
    const float* pos = (const float*)d_in[0];
    const float* scales = (const float*)d_in[1];
    const float* rots = (const float*)d_in[2];
    const float* colors = (const float*)d_in[3];
    int n = in_sizes[0] / 3;   // 8192
    int nw = n / 2;            // 4096 waves, 2 rows each

    double* partials = (double*)d_ws;

    main_kernel<<<nw / 4, 256, 0, stream>>>(pos, scales, rots, colors, partials, n);
    final_kernel<<<1, 256, 0, stream>>>(partials, (float*)d_out, nw);
}